// Round 2
// baseline (754.218 us; speedup 1.0000x reference)
//
#include <hip/hip_runtime.h>
#include <stdint.h>

#define B_ 4096
#define H_ 256
#define L_ 32
#define I_ 64
#define BH_ (B_*H_)   // 1048576

typedef unsigned short u16;
typedef unsigned int u32;
typedef __bf16 bf16_t;
typedef bf16_t bf16x8 __attribute__((ext_vector_type(8)));
typedef float f32x4 __attribute__((ext_vector_type(4)));
typedef u16 u16x8 __attribute__((ext_vector_type(8)));

__device__ __forceinline__ float b2f(u16 u) {
  union { u32 i; float f; } c; c.i = ((u32)u) << 16; return c.f;
}
__device__ __forceinline__ u16 f2bf(float f) {
  union { float f; u32 i; } c; c.f = f;
  u32 u = c.i;
  return (u16)((u + 0x7fffu + ((u >> 16) & 1u)) >> 16);
}
__device__ __forceinline__ float sigmoidf_(float v) { return 1.0f / (1.0f + __expf(-v)); }
__device__ __forceinline__ float tanhf_(float v) {
  float e = __expf(-2.0f * fabsf(v));
  float t = (1.0f - e) / (1.0f + e);
  return copysignf(t, v);
}

// ---------- transpose hidden (B,H,L) fp32 -> hT (L, B*H) bf16 ----------
__global__ __launch_bounds__(256) void k_transpose_hidden(const float* __restrict__ src,
                                                          u16* __restrict__ dst) {
  __shared__ u32 T[32 * 257];
  const int t = threadIdx.x;
  const size_t bh0 = (size_t)blockIdx.x * 256;
  {
    const float* p = src + (bh0 + t) * 32;
#pragma unroll
    for (int c = 0; c < 8; ++c) {
      f32x4 v = *(const f32x4*)(p + c * 4);
#pragma unroll
      for (int j = 0; j < 4; ++j) T[(c * 4 + j) * 257 + t] = f2bf(v[j]);
    }
  }
  __syncthreads();
  {
    const int lcol = t & 31, seg = t >> 5;  // 32 l-rows x 8 segments
    u16* q = dst + (size_t)lcol * BH_ + bh0 + seg * 32;
#pragma unroll
    for (int c = 0; c < 4; ++c) {
      u16x8 v;
#pragma unroll
      for (int j = 0; j < 8; ++j) v[j] = (u16)T[lcol * 257 + seg * 32 + c * 8 + j];
      *(u16x8*)(q + c * 8) = v;
    }
  }
}

// ---------- transpose h2 (L, B*H) bf16 -> out (B*H, L) fp32 ----------
__global__ __launch_bounds__(256) void k_transpose_out(const u16* __restrict__ src,
                                                       float* __restrict__ dst) {
  __shared__ u32 T[32 * 257];
  const int t = threadIdx.x;
  const size_t bh0 = (size_t)blockIdx.x * 256;
  {
    const int lrow = t & 31, seg = t >> 5;
    const u16* p = src + (size_t)lrow * BH_ + bh0 + seg * 32;
#pragma unroll
    for (int c = 0; c < 4; ++c) {
      u16x8 v = *(const u16x8*)(p + c * 8);
#pragma unroll
      for (int j = 0; j < 8; ++j) T[lrow * 257 + seg * 32 + c * 8 + j] = v[j];
    }
  }
  __syncthreads();
  {
    float* q = dst + (bh0 + t) * 32;
#pragma unroll
    for (int c = 0; c < 8; ++c) {
      f32x4 v;
#pragma unroll
      for (int j = 0; j < 4; ++j) v[j] = b2f((u16)T[(c * 4 + j) * 257 + t]);
      *(f32x4*)(q + c * 4) = v;
    }
  }
}

// ---------- weight transpose: src[l][k][n(256)] fp32 -> dst[l][n][k] bf16 ----------
struct WTA {
  const float* src[8];
  u16* dst[8];
};

__global__ __launch_bounds__(256) void k_transpose_w(WTA a) {
  const int m = blockIdx.z & 7, l = blockIdx.z >> 3;
  const int K = (m < 5) ? 256 : 64;
  const int k0 = blockIdx.y * 64;
  if (k0 >= K) return;
  const int n0 = blockIdx.x * 64;
  __shared__ u32 T[64 * 65];
  const int t = threadIdx.x;
  {
    const int kl = t >> 2, c = (t & 3) * 16;
    const float* p = a.src[m] + ((size_t)l * K + k0 + kl) * 256 + n0 + c;
#pragma unroll
    for (int cc = 0; cc < 4; ++cc) {
      f32x4 v = *(const f32x4*)(p + cc * 4);
#pragma unroll
      for (int j = 0; j < 4; ++j) T[kl * 65 + c + cc * 4 + j] = f2bf(v[j]);
    }
  }
  __syncthreads();
  {
    const int nl = t & 63, kq = t >> 6;
    u16* p = a.dst[m] + ((size_t)l * 256 + n0 + nl) * K + k0 + kq * 16;
#pragma unroll
    for (int cc = 0; cc < 2; ++cc) {
      u16x8 v;
#pragma unroll
      for (int j = 0; j < 8; ++j) v[j] = (u16)T[(kq * 16 + cc * 8 + j) * 65 + nl];
      *(u16x8*)(p + cc * 8) = v;
    }
  }
}

// ---------- lv fill (fp32) ----------
__global__ __launch_bounds__(256) void k_lv(const float* __restrict__ logv, float* __restrict__ dst) {
  const int idx = blockIdx.x * 256 + threadIdx.x;
  dst[idx] = fmaxf(logv[idx & 31], -3.0f);
}

// ---------- fused GRU + MLP ----------
// grid (B/64, L), 256 threads = 4 waves; wave w owns output cols [64w, 64w+64)
__global__ __launch_bounds__(256, 2) void k_fused(
    const float* __restrict__ x, const float* __restrict__ mask,
    const float* __restrict__ bir, const float* __restrict__ biz,
    const float* __restrict__ bin_, const float* __restrict__ bhn,
    const float* __restrict__ b1, const float* __restrict__ b2,
    const float* __restrict__ Wmu, const float* __restrict__ bmu,
    u16* __restrict__ hT,  // in: hT (L,B,H) bf16; out: h2 written back in place
    const u16* __restrict__ WhrT, const u16* __restrict__ WhzT,
    const u16* __restrict__ WhnT, const u16* __restrict__ W1T,
    const u16* __restrict__ W2T, const u16* __restrict__ WirT,
    const u16* __restrict__ WizT, const u16* __restrict__ WinT,
    float* __restrict__ mu_out) {
  const int l = blockIdx.y;
  const int b0 = blockIdx.x * 64;
  const int tid = threadIdx.x;

  __shared__ u16 Ah[64 * 264];   // A tile, stride 264 (132 dwords, /4 odd -> uniform banks)
  __shared__ u16 Xm[64 * 72];    // masked x tile, stride 72
  __shared__ float MuAcc[256];
  __shared__ float maskl[64];

  if (tid < 64) maskl[tid] = mask[tid * L_ + l];

  // stage A (h) tile from hT: coalesced
  {
    const int row = tid >> 2, cs = (tid & 3) * 64;
    const u16* src = hT + (size_t)l * BH_ + (size_t)(b0 + row) * H_ + cs;
    u16* dst = &Ah[row * 264 + cs];
#pragma unroll
    for (int c = 0; c < 8; ++c) *(u16x8*)(dst + c * 8) = *(const u16x8*)(src + c * 8);
  }
  __syncthreads();
  // stage Xm = bf16(x * mask[:,l])
  {
    const int row = tid >> 2, i0 = (tid & 3) * 16;
    const float* src = x + (size_t)(b0 + row) * I_ + i0;
    u16* dst = &Xm[row * 72 + i0];
#pragma unroll
    for (int c = 0; c < 2; ++c) {
      f32x4 v0 = *(const f32x4*)(src + c * 8);
      f32x4 v1 = *(const f32x4*)(src + c * 8 + 4);
      u16x8 o;
#pragma unroll
      for (int j = 0; j < 4; ++j) o[j] = (maskl[i0 + c * 8 + j] != 0.0f) ? f2bf(v0[j]) : (u16)0;
#pragma unroll
      for (int j = 0; j < 4; ++j) o[4 + j] = (maskl[i0 + c * 8 + 4 + j] != 0.0f) ? f2bf(v1[j]) : (u16)0;
      *(u16x8*)(dst + c * 8) = o;
    }
  }
  __syncthreads();

  const int w = tid >> 6, lane = tid & 63;
  const int q = lane >> 4, r15 = lane & 15;
  const int nb = w * 64;

  const size_t HH = (size_t)H_ * H_;
  const u16* WhrTl = WhrT + (size_t)l * HH;
  const u16* WhzTl = WhzT + (size_t)l * HH;
  const u16* WhnTl = WhnT + (size_t)l * HH;
  const u16* W1Tl = W1T + (size_t)l * HH;
  const u16* W2Tl = W2T + (size_t)l * HH;
  const u16* WirTl = WirT + (size_t)l * (H_ * I_);
  const u16* WizTl = WizT + (size_t)l * (H_ * I_);
  const u16* WinTl = WinT + (size_t)l * (H_ * I_);

  // K=256 GEMM: acc[mt][nt] += Ah[64x256] * WT[cols nb..nb+63]
  auto gemmH = [&](f32x4(&acc)[4][4], const u16* __restrict__ WT) {
#pragma unroll
    for (int ks = 0; ks < 8; ++ks) {
      bf16x8 bfr[4], afr[4];
#pragma unroll
      for (int nt = 0; nt < 4; ++nt)
        bfr[nt] = *(const bf16x8*)(WT + (nb + nt * 16 + r15) * 256 + ks * 32 + q * 8);
#pragma unroll
      for (int mt = 0; mt < 4; ++mt)
        afr[mt] = *(const bf16x8*)(&Ah[(mt * 16 + r15) * 264 + ks * 32 + q * 8]);
#pragma unroll
      for (int mt = 0; mt < 4; ++mt)
#pragma unroll
        for (int nt = 0; nt < 4; ++nt)
          acc[mt][nt] = __builtin_amdgcn_mfma_f32_16x16x32_bf16(afr[mt], bfr[nt], acc[mt][nt], 0, 0, 0);
    }
  };
  // K=64 GEMM from Xm
  auto gemmX = [&](f32x4(&acc)[4][4], const u16* __restrict__ WT) {
#pragma unroll
    for (int ks = 0; ks < 2; ++ks) {
      bf16x8 bfr[4], afr[4];
#pragma unroll
      for (int nt = 0; nt < 4; ++nt)
        bfr[nt] = *(const bf16x8*)(WT + (nb + nt * 16 + r15) * I_ + ks * 32 + q * 8);
#pragma unroll
      for (int mt = 0; mt < 4; ++mt)
        afr[mt] = *(const bf16x8*)(&Xm[(mt * 16 + r15) * 72 + ks * 32 + q * 8]);
#pragma unroll
      for (int mt = 0; mt < 4; ++mt)
#pragma unroll
        for (int nt = 0; nt < 4; ++nt)
          acc[mt][nt] = __builtin_amdgcn_mfma_f32_16x16x32_bf16(afr[mt], bfr[nt], acc[mt][nt], 0, 0, 0);
    }
  };
  auto zero = [&](f32x4(&acc)[4][4]) {
#pragma unroll
    for (int mt = 0; mt < 4; ++mt)
#pragma unroll
      for (int nt = 0; nt < 4; ++nt) acc[mt][nt] = f32x4{0.f, 0.f, 0.f, 0.f};
  };

  int colh[4];
  float birc[4], bizc[4], binc[4], bhnc[4], b1c[4], b2c[4], wmuc[4];
#pragma unroll
  for (int nt = 0; nt < 4; ++nt) {
    colh[nt] = nb + nt * 16 + r15;
    birc[nt] = bir[l * H_ + colh[nt]];
    bizc[nt] = biz[l * H_ + colh[nt]];
    binc[nt] = bin_[l * H_ + colh[nt]];
    bhnc[nt] = bhn[l * H_ + colh[nt]];
    b1c[nt] = b1[l * H_ + colh[nt]];
    b2c[nt] = b2[l * H_ + colh[nt]];
    wmuc[nt] = Wmu[l * H_ + colh[nt]];
  }

  // ---- GRU ----
  f32x4 accN[4][4];  // hh_n
  zero(accN);
  gemmH(accN, WhnTl);
  f32x4 accR[4][4];
  zero(accR);
  gemmX(accR, WirTl);
  gemmH(accR, WhrTl);
  // accR <- sigmoid(accR + bir) * (accN + bhn)   [= r * (hh_n + bhn)]
#pragma unroll
  for (int mt = 0; mt < 4; ++mt)
#pragma unroll
    for (int nt = 0; nt < 4; ++nt)
#pragma unroll
      for (int e = 0; e < 4; ++e) {
        float r = sigmoidf_(accR[mt][nt][e] + birc[nt]);
        accR[mt][nt][e] = r * (accN[mt][nt][e] + bhnc[nt]);
      }
  f32x4 accX[4][4];  // xi_n -> n
  zero(accX);
  gemmX(accX, WinTl);
#pragma unroll
  for (int mt = 0; mt < 4; ++mt)
#pragma unroll
    for (int nt = 0; nt < 4; ++nt)
#pragma unroll
      for (int e = 0; e < 4; ++e)
        accX[mt][nt][e] = tanhf_(accX[mt][nt][e] + binc[nt] + accR[mt][nt][e]);
  f32x4 accZ[4][4];
  zero(accZ);
  gemmX(accZ, WizTl);
  gemmH(accZ, WhzTl);
  // hnew = (1-z)*n + z*h   (h read from Ah at C/D positions)
#pragma unroll
  for (int mt = 0; mt < 4; ++mt)
#pragma unroll
    for (int nt = 0; nt < 4; ++nt)
#pragma unroll
      for (int e = 0; e < 4; ++e) {
        float z = sigmoidf_(accZ[mt][nt][e] + bizc[nt]);
        float hv = b2f(Ah[(mt * 16 + q * 4 + e) * 264 + colh[nt]]);
        accZ[mt][nt][e] = (1.0f - z) * accX[mt][nt][e] + z * hv;
      }
  __syncthreads();  // everyone done reading Ah (h)
#pragma unroll
  for (int mt = 0; mt < 4; ++mt)
#pragma unroll
    for (int nt = 0; nt < 4; ++nt)
#pragma unroll
      for (int e = 0; e < 4; ++e)
        Ah[(mt * 16 + q * 4 + e) * 264 + colh[nt]] = f2bf(accZ[mt][nt][e]);
  __syncthreads();

  // ---- MLP layer 1 ----
  f32x4 acc1[4][4];
  zero(acc1);
  gemmH(acc1, W1Tl);
#pragma unroll
  for (int mt = 0; mt < 4; ++mt)
#pragma unroll
    for (int nt = 0; nt < 4; ++nt)
#pragma unroll
      for (int e = 0; e < 4; ++e) acc1[mt][nt][e] = fmaxf(acc1[mt][nt][e] + b1c[nt], 0.0f);
  __syncthreads();  // done reading hnew
#pragma unroll
  for (int mt = 0; mt < 4; ++mt)
#pragma unroll
    for (int nt = 0; nt < 4; ++nt)
#pragma unroll
      for (int e = 0; e < 4; ++e)
        Ah[(mt * 16 + q * 4 + e) * 264 + colh[nt]] = f2bf(acc1[mt][nt][e]);
  __syncthreads();

  // ---- MLP layer 2 ----
  f32x4 acc2[4][4];
  zero(acc2);
  gemmH(acc2, W2Tl);
#pragma unroll
  for (int mt = 0; mt < 4; ++mt)
#pragma unroll
    for (int nt = 0; nt < 4; ++nt)
#pragma unroll
      for (int e = 0; e < 4; ++e) acc2[mt][nt][e] = fmaxf(acc2[mt][nt][e] + b2c[nt], 0.0f);

  // ---- mu partials: reduce over cols (r15 within quad) ----
  float mup[4][4];
#pragma unroll
  for (int mt = 0; mt < 4; ++mt)
#pragma unroll
    for (int e = 0; e < 4; ++e) {
      float s = 0.f;
#pragma unroll
      for (int nt = 0; nt < 4; ++nt) s += acc2[mt][nt][e] * wmuc[nt];
      mup[mt][e] = s;
    }
#pragma unroll
  for (int off = 1; off < 16; off <<= 1)
#pragma unroll
    for (int mt = 0; mt < 4; ++mt)
#pragma unroll
      for (int e = 0; e < 4; ++e) mup[mt][e] += __shfl_xor(mup[mt][e], off, 64);
  if (r15 == 0) {
#pragma unroll
    for (int mt = 0; mt < 4; ++mt)
#pragma unroll
      for (int e = 0; e < 4; ++e) MuAcc[w * 64 + mt * 16 + q * 4 + e] = mup[mt][e];
  }
  __syncthreads();  // also: done reading Ah (h1)
#pragma unroll
  for (int mt = 0; mt < 4; ++mt)
#pragma unroll
    for (int nt = 0; nt < 4; ++nt)
#pragma unroll
      for (int e = 0; e < 4; ++e)
        Ah[(mt * 16 + q * 4 + e) * 264 + colh[nt]] = f2bf(acc2[mt][nt][e]);
  __syncthreads();

  // ---- write h2 tile back to hT region (coalesced) + mu ----
  {
    const int row = tid >> 2, cs = (tid & 3) * 64;
    u16* dst = hT + (size_t)l * BH_ + (size_t)(b0 + row) * H_ + cs;
#pragma unroll
    for (int c = 0; c < 8; ++c) *(u16x8*)(dst + c * 8) = *(const u16x8*)(&Ah[row * 264 + cs + c * 8]);
  }
  if (tid < 64) {
    float m = MuAcc[tid] + MuAcc[64 + tid] + MuAcc[128 + tid] + MuAcc[192 + tid] + bmu[l];
    mu_out[(size_t)(b0 + tid) * L_ + l] = m;
  }
}

extern "C" void kernel_launch(void* const* d_in, const int* in_sizes, int n_in,
                              void* d_out, int out_size, void* d_ws, size_t ws_size,
                              hipStream_t stream) {
  (void)in_sizes; (void)n_in; (void)out_size; (void)ws_size;
  const float* hidden = (const float*)d_in[0];
  const float* x = (const float*)d_in[1];
  const float* mask = (const float*)d_in[2];
  const float* Wir = (const float*)d_in[3];
  const float* bir = (const float*)d_in[4];
  const float* Wiz = (const float*)d_in[5];
  const float* biz = (const float*)d_in[6];
  const float* Win = (const float*)d_in[7];
  const float* bin_ = (const float*)d_in[8];
  const float* Whr = (const float*)d_in[9];
  const float* Whz = (const float*)d_in[10];
  const float* Whn = (const float*)d_in[11];
  const float* bhn = (const float*)d_in[12];
  const float* W1 = (const float*)d_in[13];
  const float* b1 = (const float*)d_in[14];
  const float* W2 = (const float*)d_in[15];
  const float* b2 = (const float*)d_in[16];
  const float* Wmu = (const float*)d_in[17];
  const float* bmu = (const float*)d_in[18];
  const float* logv = (const float*)d_in[19];
  float* out = (float*)d_out;

  // ws layout (u16 elements): hT(+h2) bf16 | 5x hiddenWT | 3x inputWT  = ~91 MB
  u16* ws = (u16*)d_ws;
  u16* hT = ws;                                   // L*B*H = 33554432
  u16* WhrT = ws + (size_t)33554432;
  u16* WhzT = WhrT + 2097152;
  u16* WhnT = WhzT + 2097152;
  u16* W1T = WhnT + 2097152;
  u16* W2T = W1T + 2097152;
  u16* WirT = W2T + 2097152;
  u16* WizT = WirT + 524288;
  u16* WinT = WizT + 524288;

  k_transpose_hidden<<<dim3(BH_ / 256), dim3(256), 0, stream>>>(hidden, hT);

  WTA wta;
  wta.src[0] = Whr; wta.dst[0] = WhrT;
  wta.src[1] = Whz; wta.dst[1] = WhzT;
  wta.src[2] = Whn; wta.dst[2] = WhnT;
  wta.src[3] = W1;  wta.dst[3] = W1T;
  wta.src[4] = W2;  wta.dst[4] = W2T;
  wta.src[5] = Wir; wta.dst[5] = WirT;
  wta.src[6] = Wiz; wta.dst[6] = WizT;
  wta.src[7] = Win; wta.dst[7] = WinT;
  k_transpose_w<<<dim3(4, 4, 256), dim3(256), 0, stream>>>(wta);

  float* mu_out = out + (size_t)BH_ * L_;
  k_fused<<<dim3(B_ / 64, L_), dim3(256), 0, stream>>>(
      x, mask, bir, biz, bin_, bhn, b1, b2, Wmu, bmu, hT,
      WhrT, WhzT, WhnT, W1T, W2T, WirT, WizT, WinT, mu_out);

  k_transpose_out<<<dim3(BH_ / 256), dim3(256), 0, stream>>>(hT, out);
  k_lv<<<dim3((B_ * L_) / 256), dim3(256), 0, stream>>>(logv, mu_out + (size_t)B_ * L_);
}

// Round 3
// 568.460 us; speedup vs baseline: 1.3268x; 1.3268x over previous
//
#include <hip/hip_runtime.h>
#include <stdint.h>

#define B_ 4096
#define H_ 256
#define L_ 32
#define I_ 64
#define BH_ (B_*H_)   // 1048576

typedef unsigned short u16;
typedef unsigned int u32;
typedef __bf16 bf16_t;
typedef bf16_t bf16x8 __attribute__((ext_vector_type(8)));
typedef float f32x4 __attribute__((ext_vector_type(4)));
typedef u16 u16x8 __attribute__((ext_vector_type(8)));

__device__ __forceinline__ float b2f(u16 u) {
  union { u32 i; float f; } c; c.i = ((u32)u) << 16; return c.f;
}
__device__ __forceinline__ u16 f2bf(float f) {
  union { float f; u32 i; } c; c.f = f;
  u32 u = c.i;
  return (u16)((u + 0x7fffu + ((u >> 16) & 1u)) >> 16);
}
__device__ __forceinline__ float sigmoidf_(float v) { return 1.0f / (1.0f + __expf(-v)); }
__device__ __forceinline__ float tanhf_(float v) {
  float e = __expf(-2.0f * fabsf(v));
  float t = (1.0f - e) / (1.0f + e);
  return copysignf(t, v);
}

// async global->LDS 16B per lane: lds base is wave-uniform, HW adds lane*16
__device__ __forceinline__ void async16(const void* g, void* l) {
  __builtin_amdgcn_global_load_lds(
      (const __attribute__((address_space(1))) unsigned int*)g,
      (__attribute__((address_space(3))) unsigned int*)l, 16, 0, 0);
}
#define WAITV asm volatile("s_waitcnt vmcnt(0)" ::: "memory")

// ---------- transpose hidden (B,H,L) fp32 -> hT (L,B,H) bf16, granule-swizzled ----------
// granule g (8 u16) of row b stored at slot (g&24)|((g&7)^(b&7))
__global__ __launch_bounds__(256) void k_transpose_hidden(const float* __restrict__ src,
                                                          u16* __restrict__ dst) {
  __shared__ u32 T[32 * 257];
  const int t = threadIdx.x;
  const int b = blockIdx.x;            // one b-row (256 h) per block
  const int bx7 = b & 7;
  {
    const float* p = src + ((size_t)b * 256 + t) * 32;
#pragma unroll
    for (int c = 0; c < 8; ++c) {
      f32x4 v = *(const f32x4*)(p + c * 4);
#pragma unroll
      for (int j = 0; j < 4; ++j) T[(c * 4 + j) * 257 + t] = f2bf(v[j]);
    }
  }
  __syncthreads();
  {
    const int lcol = t & 31, seg = t >> 5;  // 32 l-rows x 8 h-segments
#pragma unroll
    for (int c = 0; c < 4; ++c) {
      const int g = seg * 4 + c;
      const int slot = (g & 24) | ((g & 7) ^ bx7);
      u16x8 v;
#pragma unroll
      for (int j = 0; j < 8; ++j) v[j] = (u16)T[lcol * 257 + g * 8 + j];
      *(u16x8*)(dst + (size_t)lcol * BH_ + (size_t)b * 256 + slot * 8) = v;
    }
  }
}

// ---------- transpose h2 hT(L,B,H swizzled bf16) -> out (B,H,L) fp32 ----------
__global__ __launch_bounds__(256) void k_transpose_out(const u16* __restrict__ src,
                                                       float* __restrict__ dst) {
  __shared__ u32 T[32 * 257];
  const int t = threadIdx.x;
  const int b = blockIdx.x;
  const int bx7 = b & 7;
  {
    const int lrow = t & 31, seg = t >> 5;
#pragma unroll
    for (int c = 0; c < 4; ++c) {
      const int g = seg * 4 + c;
      const int slot = (g & 24) | ((g & 7) ^ bx7);
      u16x8 v = *(const u16x8*)(src + (size_t)lrow * BH_ + (size_t)b * 256 + slot * 8);
#pragma unroll
      for (int j = 0; j < 8; ++j) T[lrow * 257 + g * 8 + j] = v[j];
    }
  }
  __syncthreads();
  {
    float* q = dst + ((size_t)b * 256 + t) * 32;
#pragma unroll
    for (int c = 0; c < 8; ++c) {
      f32x4 v;
#pragma unroll
      for (int j = 0; j < 4; ++j) v[j] = b2f((u16)T[(c * 4 + j) * 257 + t]);
      *(f32x4*)(q + c * 4) = v;
    }
  }
}

// ---------- weight transpose: src[l][k][n] fp32 -> chunked swizzled bf16 ----------
// hidden (K=256): dst[l][chunk=k/64][n][64k'], granule gl=klocal/8 at slot gl^(n&7)
// input  (K=64):  dst[l][n][64k'] same swizzle
struct WTA {
  const float* src[8];
  u16* dst[8];
};

__global__ __launch_bounds__(256) void k_transpose_w(WTA a) {
  const int m = blockIdx.z & 7, l = blockIdx.z >> 3;
  const int K = (m < 5) ? 256 : 64;
  const int k0 = blockIdx.y * 64;
  if (k0 >= K) return;
  const int n0 = blockIdx.x * 64;
  __shared__ u32 T[64 * 65];
  const int t = threadIdx.x;
  {
    const int kl = t >> 2, c = (t & 3) * 16;
    const float* p = a.src[m] + ((size_t)l * K + k0 + kl) * 256 + n0 + c;
#pragma unroll
    for (int cc = 0; cc < 4; ++cc) {
      f32x4 v = *(const f32x4*)(p + cc * 4);
#pragma unroll
      for (int j = 0; j < 4; ++j) T[kl * 65 + c + cc * 4 + j] = f2bf(v[j]);
    }
  }
  __syncthreads();
  {
    const int nl = t & 63, kq = t >> 6;
    const int n = n0 + nl;
    const size_t base = (m < 5) ? (((size_t)l * 4 + (k0 >> 6)) * 256 + n) * 64
                                : ((size_t)l * 256 + n) * 64;
#pragma unroll
    for (int cc = 0; cc < 2; ++cc) {
      const int gl = kq * 2 + cc;
      const int slot = gl ^ (n & 7);
      u16x8 v;
#pragma unroll
      for (int j = 0; j < 8; ++j) v[j] = (u16)T[(gl * 8 + j) * 65 + nl];
      *(u16x8*)(a.dst[m] + base + slot * 8) = v;
    }
  }
}

// ---------- lv fill (fp32) ----------
__global__ __launch_bounds__(256) void k_lv(const float* __restrict__ logv, float* __restrict__ dst) {
  const int idx = blockIdx.x * 256 + threadIdx.x;
  dst[idx] = fmaxf(logv[idx & 31], -3.0f);
}

// ---------- fused GRU + MLP, m97-style LDS-staged weights ----------
// grid (B/64, L), 256 threads = 4 waves; wave w owns output cols [64w,64w+64)
__global__ __launch_bounds__(256, 2) void k_fused(
    const float* __restrict__ x, const float* __restrict__ mask,
    const float* __restrict__ bir, const float* __restrict__ biz,
    const float* __restrict__ bin_, const float* __restrict__ bhn,
    const float* __restrict__ b1, const float* __restrict__ b2,
    const float* __restrict__ Wmu, const float* __restrict__ bmu,
    u16* __restrict__ hT,  // in: h (swizzled); out: h2 (same layout), in place
    const u16* __restrict__ WhrT, const u16* __restrict__ WhzT,
    const u16* __restrict__ WhnT, const u16* __restrict__ W1T,
    const u16* __restrict__ W2T, const u16* __restrict__ WirT,
    const u16* __restrict__ WizT, const u16* __restrict__ WinT,
    float* __restrict__ mu_out) {
  const int l = blockIdx.y;
  const int b0 = blockIdx.x * 64;
  const int tid = threadIdx.x;
  const int w = tid >> 6, lane = tid & 63;
  const int q = lane >> 4, r15 = lane & 15;
  const int xr = r15 & 7;
  const int nb = w * 64;

  __shared__ u16 Ah[64 * 256];    // A tile, swizzled granules (no pad needed)
  __shared__ u16 Wbuf[256 * 64];  // one 32KB weight chunk [n][64k], swizzled
  __shared__ u16 Xm[64 * 64];     // masked x tile, swizzled granules
  __shared__ float MuAcc[256];

  // ---- stage A tile: pure 32KB DMA copy (layouts identical incl. swizzle) ----
  {
    const char* g = (const char*)(hT + ((size_t)l * B_ + b0) * 256);
    char* lb = (char*)Ah;
#pragma unroll
    for (int i = 0; i < 8; ++i) {
      const int o = i * 4096 + w * 1024;
      async16(g + o + lane * 16, lb + o);
    }
  }
  auto stageW = [&](const u16* cbase) {
    const char* g = (const char*)cbase;
    char* lb = (char*)Wbuf;
#pragma unroll
    for (int i = 0; i < 8; ++i) {
      const int o = (w * 8 + i) * 1024;
      async16(g + o + lane * 16, lb + o);
    }
  };
  stageW(WhnT + (size_t)l * 65536);  // Whn chunk 0

  // ---- stage Xm = bf16(x * mask[:,l]) via VGPR (needs transform) ----
  {
    const int row = tid >> 2, qq = tid & 3;
    const float* xs = x + (size_t)(b0 + row) * I_ + qq * 16;
    f32x4 v0 = *(const f32x4*)(xs);
    f32x4 v1 = *(const f32x4*)(xs + 4);
    f32x4 v2 = *(const f32x4*)(xs + 8);
    f32x4 v3 = *(const f32x4*)(xs + 12);
    float mv[16];
#pragma unroll
    for (int j = 0; j < 16; ++j) mv[j] = mask[(qq * 16 + j) * L_ + l];
    u16x8 o0, o1;
#pragma unroll
    for (int j = 0; j < 4; ++j) {
      o0[j] = (mv[j] != 0.0f) ? f2bf(v0[j]) : (u16)0;
      o0[4 + j] = (mv[4 + j] != 0.0f) ? f2bf(v1[j]) : (u16)0;
      o1[j] = (mv[8 + j] != 0.0f) ? f2bf(v2[j]) : (u16)0;
      o1[4 + j] = (mv[12 + j] != 0.0f) ? f2bf(v3[j]) : (u16)0;
    }
    const int r7 = row & 7;
    *(u16x8*)(Xm + row * 64 + ((qq * 2) ^ r7) * 8) = o0;
    *(u16x8*)(Xm + row * 64 + ((qq * 2 + 1) ^ r7) * 8) = o1;
  }

  int Arow[4], Wcol[4], Xrow[4], colh[4];
  float birc[4], bizc[4], binc[4], bhnc[4], b1c[4], b2c[4], wmuc[4];
#pragma unroll
  for (int nt = 0; nt < 4; ++nt) {
    colh[nt] = nb + nt * 16 + r15;
    Arow[nt] = (nt * 16 + r15) * 256;  // also used as mt row base
    Xrow[nt] = (nt * 16 + r15) * 64;
    Wcol[nt] = colh[nt] * 64;
    birc[nt] = bir[l * H_ + colh[nt]];
    bizc[nt] = biz[l * H_ + colh[nt]];
    binc[nt] = bin_[l * H_ + colh[nt]];
    bhnc[nt] = bhn[l * H_ + colh[nt]];
    b1c[nt] = b1[l * H_ + colh[nt]];
    b2c[nt] = b2[l * H_ + colh[nt]];
    wmuc[nt] = Wmu[l * H_ + colh[nt]];
  }

  // swizzled Ah scalar index for (row r, col c)
  auto ahIdx = [&](int r, int c) {
    const int g = c >> 3;
    const int slot = (g & 24) | ((g & 7) ^ (r & 7));
    return r * 256 + slot * 8 + (c & 7);
  };

  // K=64 chunk of a K=256 GEMM: 2 MFMA k-steps
  auto computeH = [&](f32x4(&acc)[4][4], int c) {
#pragma unroll
    for (int ksub = 0; ksub < 2; ++ksub) {
      const int ga = c * 8 + ksub * 4 + q;
      const int sa = ((ga & 24) | ((ga & 7) ^ xr)) * 8;
      const int sw = (((ksub * 4 + q) ^ xr)) * 8;
      bf16x8 bfr[4], afr[4];
#pragma unroll
      for (int nt = 0; nt < 4; ++nt) bfr[nt] = *(const bf16x8*)(Wbuf + Wcol[nt] + sw);
#pragma unroll
      for (int mt = 0; mt < 4; ++mt) afr[mt] = *(const bf16x8*)(Ah + Arow[mt] + sa);
#pragma unroll
      for (int mt = 0; mt < 4; ++mt)
#pragma unroll
        for (int nt = 0; nt < 4; ++nt)
          acc[mt][nt] = __builtin_amdgcn_mfma_f32_16x16x32_bf16(afr[mt], bfr[nt], acc[mt][nt], 0, 0, 0);
    }
  };
  // whole K=64 X-GEMM from Xm
  auto computeX = [&](f32x4(&acc)[4][4]) {
#pragma unroll
    for (int ksx = 0; ksx < 2; ++ksx) {
      const int s = (((ksx * 4 + q) ^ xr)) * 8;
      bf16x8 bfr[4], afr[4];
#pragma unroll
      for (int nt = 0; nt < 4; ++nt) bfr[nt] = *(const bf16x8*)(Wbuf + Wcol[nt] + s);
#pragma unroll
      for (int mt = 0; mt < 4; ++mt) afr[mt] = *(const bf16x8*)(Xm + Xrow[mt] + s);
#pragma unroll
      for (int mt = 0; mt < 4; ++mt)
#pragma unroll
        for (int nt = 0; nt < 4; ++nt)
          acc[mt][nt] = __builtin_amdgcn_mfma_f32_16x16x32_bf16(afr[mt], bfr[nt], acc[mt][nt], 0, 0, 0);
    }
  };
  auto zero = [&](f32x4(&acc)[4][4]) {
#pragma unroll
    for (int mt = 0; mt < 4; ++mt)
#pragma unroll
      for (int nt = 0; nt < 4; ++nt) acc[mt][nt] = f32x4{0.f, 0.f, 0.f, 0.f};
  };

  const u16* whn = WhnT + (size_t)l * 65536;
  const u16* whr = WhrT + (size_t)l * 65536;
  const u16* whz = WhzT + (size_t)l * 65536;
  const u16* w1p = W1T + (size_t)l * 65536;
  const u16* w2p = W2T + (size_t)l * 65536;
  const u16* wir = WirT + (size_t)l * 16384;
  const u16* wiz = WizT + (size_t)l * 16384;
  const u16* win = WinT + (size_t)l * 16384;

  // ---- GRU: accN = Whn*h ----
  f32x4 accN[4][4]; zero(accN);
  WAITV; __syncthreads();
  computeH(accN, 0); __syncthreads();
#pragma unroll
  for (int c = 1; c < 4; ++c) {
    stageW(whn + c * 16384); WAITV; __syncthreads();
    computeH(accN, c); __syncthreads();
  }
  // accR = Whr*h + Wir*xm
  f32x4 accR[4][4]; zero(accR);
#pragma unroll
  for (int c = 0; c < 4; ++c) {
    stageW(whr + c * 16384); WAITV; __syncthreads();
    computeH(accR, c); __syncthreads();
  }
  stageW(wir); WAITV; __syncthreads();
  computeX(accR); __syncthreads();
  stageW(win);
  // elemwise: accR <- sigmoid(accR+bir) * (accN + bhn)  (overlaps win DMA)
#pragma unroll
  for (int mt = 0; mt < 4; ++mt)
#pragma unroll
    for (int nt = 0; nt < 4; ++nt)
#pragma unroll
      for (int e = 0; e < 4; ++e) {
        float r = sigmoidf_(accR[mt][nt][e] + birc[nt]);
        accR[mt][nt][e] = r * (accN[mt][nt][e] + bhnc[nt]);
      }
  f32x4 accX[4][4]; zero(accX);
  WAITV; __syncthreads();
  computeX(accX); __syncthreads();
  stageW(whz);
  // n = tanh(xi_n + bin + accR)  (overlaps whz c0 DMA)
#pragma unroll
  for (int mt = 0; mt < 4; ++mt)
#pragma unroll
    for (int nt = 0; nt < 4; ++nt)
#pragma unroll
      for (int e = 0; e < 4; ++e)
        accX[mt][nt][e] = tanhf_(accX[mt][nt][e] + binc[nt] + accR[mt][nt][e]);
  f32x4 accZ[4][4]; zero(accZ);
  WAITV; __syncthreads();
  computeH(accZ, 0); __syncthreads();
#pragma unroll
  for (int c = 1; c < 4; ++c) {
    stageW(whz + c * 16384); WAITV; __syncthreads();
    computeH(accZ, c); __syncthreads();
  }
  stageW(wiz); WAITV; __syncthreads();
  computeX(accZ); __syncthreads();
  stageW(w1p);
  // hnew = (1-z)*n + z*h ; write into Ah (disjoint per-lane positions)
#pragma unroll
  for (int mt = 0; mt < 4; ++mt)
#pragma unroll
    for (int nt = 0; nt < 4; ++nt)
#pragma unroll
      for (int e = 0; e < 4; ++e) {
        float z = sigmoidf_(accZ[mt][nt][e] + bizc[nt]);
        float hv = b2f(Ah[ahIdx(mt * 16 + q * 4 + e, colh[nt])]);
        Ah[ahIdx(mt * 16 + q * 4 + e, colh[nt])] = f2bf((1.0f - z) * accX[mt][nt][e] + z * hv);
      }
  // ---- MLP1 ----
  f32x4 acc1[4][4]; zero(acc1);
  WAITV; __syncthreads();
  computeH(acc1, 0); __syncthreads();
#pragma unroll
  for (int c = 1; c < 4; ++c) {
    stageW(w1p + c * 16384); WAITV; __syncthreads();
    computeH(acc1, c); __syncthreads();
  }
  stageW(w2p);
#pragma unroll
  for (int mt = 0; mt < 4; ++mt)
#pragma unroll
    for (int nt = 0; nt < 4; ++nt)
#pragma unroll
      for (int e = 0; e < 4; ++e)
        Ah[ahIdx(mt * 16 + q * 4 + e, colh[nt])] = f2bf(fmaxf(acc1[mt][nt][e] + b1c[nt], 0.0f));
  // ---- MLP2 ----
  f32x4 acc2[4][4]; zero(acc2);
  WAITV; __syncthreads();
  computeH(acc2, 0); __syncthreads();
#pragma unroll
  for (int c = 1; c < 4; ++c) {
    stageW(w2p + c * 16384); WAITV; __syncthreads();
    computeH(acc2, c); __syncthreads();
  }
#pragma unroll
  for (int mt = 0; mt < 4; ++mt)
#pragma unroll
    for (int nt = 0; nt < 4; ++nt)
#pragma unroll
      for (int e = 0; e < 4; ++e) acc2[mt][nt][e] = fmaxf(acc2[mt][nt][e] + b2c[nt], 0.0f);

  // mu partials: dot with Wmu over cols, reduce across r15
  float mup[4][4];
#pragma unroll
  for (int mt = 0; mt < 4; ++mt)
#pragma unroll
    for (int e = 0; e < 4; ++e) {
      float s = 0.f;
#pragma unroll
      for (int nt = 0; nt < 4; ++nt) s += acc2[mt][nt][e] * wmuc[nt];
      mup[mt][e] = s;
    }
#pragma unroll
  for (int off = 1; off < 16; off <<= 1)
#pragma unroll
    for (int mt = 0; mt < 4; ++mt)
#pragma unroll
      for (int e = 0; e < 4; ++e) mup[mt][e] += __shfl_xor(mup[mt][e], off, 64);
  if (r15 == 0) {
#pragma unroll
    for (int mt = 0; mt < 4; ++mt)
#pragma unroll
      for (int e = 0; e < 4; ++e) MuAcc[w * 64 + mt * 16 + q * 4 + e] = mup[mt][e];
  }
  // h2 -> Ah
#pragma unroll
  for (int mt = 0; mt < 4; ++mt)
#pragma unroll
    for (int nt = 0; nt < 4; ++nt)
#pragma unroll
      for (int e = 0; e < 4; ++e)
        Ah[ahIdx(mt * 16 + q * 4 + e, colh[nt])] = f2bf(acc2[mt][nt][e]);
  __syncthreads();

  // write h2 tile back (verbatim swizzled copy, coalesced 1KB/wave-instr)
  {
    u16* gdst = hT + ((size_t)l * B_ + b0) * 256;
#pragma unroll
    for (int i = 0; i < 8; ++i) {
      const int o = i * 2048 + tid * 8;
      *(u16x8*)(gdst + o) = *(const u16x8*)(Ah + o);
    }
  }
  if (tid < 64) {
    float m = MuAcc[tid] + MuAcc[64 + tid] + MuAcc[128 + tid] + MuAcc[192 + tid] + bmu[l];
    mu_out[(size_t)(b0 + tid) * L_ + l] = m;
  }
}

extern "C" void kernel_launch(void* const* d_in, const int* in_sizes, int n_in,
                              void* d_out, int out_size, void* d_ws, size_t ws_size,
                              hipStream_t stream) {
  (void)in_sizes; (void)n_in; (void)out_size; (void)ws_size;
  const float* hidden = (const float*)d_in[0];
  const float* x = (const float*)d_in[1];
  const float* mask = (const float*)d_in[2];
  const float* Wir = (const float*)d_in[3];
  const float* bir = (const float*)d_in[4];
  const float* Wiz = (const float*)d_in[5];
  const float* biz = (const float*)d_in[6];
  const float* Win = (const float*)d_in[7];
  const float* bin_ = (const float*)d_in[8];
  const float* Whr = (const float*)d_in[9];
  const float* Whz = (const float*)d_in[10];
  const float* Whn = (const float*)d_in[11];
  const float* bhn = (const float*)d_in[12];
  const float* W1 = (const float*)d_in[13];
  const float* b1 = (const float*)d_in[14];
  const float* W2 = (const float*)d_in[15];
  const float* b2 = (const float*)d_in[16];
  const float* Wmu = (const float*)d_in[17];
  const float* bmu = (const float*)d_in[18];
  const float* logv = (const float*)d_in[19];
  float* out = (float*)d_out;

  u16* ws = (u16*)d_ws;
  u16* hT = ws;                                   // L*B*H = 33554432 u16
  u16* WhrT = ws + (size_t)33554432;
  u16* WhzT = WhrT + 2097152;
  u16* WhnT = WhzT + 2097152;
  u16* W1T = WhnT + 2097152;
  u16* W2T = W1T + 2097152;
  u16* WirT = W2T + 2097152;
  u16* WizT = WirT + 524288;
  u16* WinT = WizT + 524288;

  k_transpose_hidden<<<dim3(B_), dim3(256), 0, stream>>>(hidden, hT);

  WTA wta;
  wta.src[0] = Whr; wta.dst[0] = WhrT;
  wta.src[1] = Whz; wta.dst[1] = WhzT;
  wta.src[2] = Whn; wta.dst[2] = WhnT;
  wta.src[3] = W1;  wta.dst[3] = W1T;
  wta.src[4] = W2;  wta.dst[4] = W2T;
  wta.src[5] = Wir; wta.dst[5] = WirT;
  wta.src[6] = Wiz; wta.dst[6] = WizT;
  wta.src[7] = Win; wta.dst[7] = WinT;
  k_transpose_w<<<dim3(4, 4, 256), dim3(256), 0, stream>>>(wta);

  float* mu_out = out + (size_t)BH_ * L_;
  k_fused<<<dim3(B_ / 64, L_), dim3(256), 0, stream>>>(
      x, mask, bir, biz, bin_, bhn, b1, b2, Wmu, bmu, hT,
      WhrT, WhzT, WhnT, W1T, W2T, WirT, WizT, WinT, mu_out);

  k_transpose_out<<<dim3(B_), dim3(256), 0, stream>>>(hT, out);
  k_lv<<<dim3((B_ * L_) / 256), dim3(256), 0, stream>>>(logv, mu_out + (size_t)B_ * L_);
}